// Round 15
// baseline (318.786 us; speedup 1.0000x reference)
//
#include <hip/hip_runtime.h>
#include <hip/hip_bf16.h>
#include <math.h>

#define N_NODES 100000
#define E_EDGES 1600000
#define ETOT    (E_EDGES + N_NODES)
#define NEG     0.2f

#define SCAN_CHUNK 1024
#define NBLK_SCAN  ((N_NODES + SCAN_CHUNK - 1) / SCAN_CHUNK)   // 98

// bucketed CSR build
#define SH        8
#define NBUCK     ((N_NODES + 255) >> 8)          // 391
#define BIN_TILE  4096
#define NBIN      ((E_EDGES + BIN_TILE - 1) / BIN_TILE)  // 391
#define LDS_CAP   6016

// hist: 8 edges/thread -> 782 blocks; mfma gemm1: 64 nodes/block -> 1563
#define NHIST     ((E_EDGES + 2047) / 2048)       // 782
#define NMFMA     ((N_NODES + 63) / 64)           // 1563

typedef __attribute__((ext_vector_type(8))) short bf16x8;
typedef __attribute__((ext_vector_type(4))) float f32x4;
typedef __attribute__((ext_vector_type(2))) short bf16p;

__device__ inline float lrelu(float x) { return x > 0.f ? x : NEG * x; }
__device__ inline float bflo(unsigned int b) { return __uint_as_float(b << 16); }
__device__ inline float bfhi(unsigned int b) { return __uint_as_float(b & 0xFFFF0000u); }
__device__ inline unsigned short f2bf(float f) {   // RNE bf16 bits
    unsigned int u = __float_as_uint(f);
    return (unsigned short)((u + 0x7FFFu + ((u >> 16) & 1u)) >> 16);
}

// dot of 2 bf16 pairs with f32 accumulate
__device__ inline float dot2bf(unsigned int wp, unsigned int hp, float c) {
#if __has_builtin(__builtin_amdgcn_fdot2_f32_bf16)
    return __builtin_amdgcn_fdot2_f32_bf16(__builtin_bit_cast(bf16p, wp),
                                           __builtin_bit_cast(bf16p, hp),
                                           c, false);
#else
    return fmaf(bflo(wp), bflo(hp), fmaf(bfhi(wp), bfhi(hp), c));
#endif
}

// ---------------- W1^T -> bf16 (one-off, 32 KB) -----------------------------
__global__ __launch_bounds__(256) void k_wt(const float* __restrict__ W,
                                            unsigned short* __restrict__ wtg) {
    int t = blockIdx.x * 256 + threadIdx.x;   // t = n*128 + k
    if (t >= 128 * 128) return;
    int n = t >> 7, k = t & 127;
    wtg[t] = f2bf(W[k * 128 + n]);
}

// ---------------- kernel A: hist || MFMA gemm1 (bf16, W^T from global) ------
__global__ __launch_bounds__(256) void k_parA(
    const int* __restrict__ dst, int* __restrict__ deg,
    const float* __restrict__ x, const unsigned short* __restrict__ wtg,
    const float* __restrict__ asrc, const float* __restrict__ adst,
    __hip_bfloat16* __restrict__ h1b, float* __restrict__ s1,
    float* __restrict__ d1) {
    __shared__ unsigned short xb[64][136];
    int bid = blockIdx.x, t = threadIdx.x;
    bool isHist = (bid % 3 == 0) && (bid / 3 < NHIST);
    if (isHist) {
        int hid = bid / 3;
        int e0 = hid * 2048 + t * 8;
#pragma unroll
        for (int half = 0; half < 2; ++half) {
            int e = e0 + half * 4;
            if (e + 3 < E_EDGES) {
                int4 v = *(const int4*)(dst + e);
                atomicAdd(&deg[v.x], 1);
                atomicAdd(&deg[v.y], 1);
                atomicAdd(&deg[v.z], 1);
                atomicAdd(&deg[v.w], 1);
            } else {
                for (int i = 0; i < 4; ++i)
                    if (e + i < E_EDGES) atomicAdd(&deg[dst[e + i]], 1);
            }
        }
        return;
    }
    int gid = bid - bid / 3 - 1;          // 0..NMFMA-1
    int n0 = gid * 64;

    // stage x tile (64x128 fp32 -> bf16), float4 coalesced, 2-way LDS writes
#pragma unroll
    for (int i = 0; i < 8; ++i) {
        int i4 = t + i * 256;
        int r = i4 >> 5;
        int c = (i4 & 31) * 4;
        float4 v = make_float4(0.f, 0.f, 0.f, 0.f);
        if (n0 + r < N_NODES) v = *(const float4*)(x + (size_t)(n0 + r) * 128 + c);
        xb[r][c + 0] = f2bf(v.x);
        xb[r][c + 1] = f2bf(v.y);
        xb[r][c + 2] = f2bf(v.z);
        xb[r][c + 3] = f2bf(v.w);
    }
    __syncthreads();

    int l = t & 63, wv = t >> 6;
    int col = l & 15, q4 = l >> 4;
    int rbase = wv * 16;
    int koff = q4 * 8;

    bf16x8 a[4];
#pragma unroll
    for (int st = 0; st < 4; ++st)
        a[st] = *(const bf16x8*)&xb[rbase + col][st * 32 + koff];

    int nodeb = n0 + rbase + q4 * 4;
#pragma unroll
    for (int nt = 0; nt < 8; ++nt) {
        f32x4 acc = {0.f, 0.f, 0.f, 0.f};
        const unsigned short* wrow = wtg + (size_t)(nt * 16 + col) * 128 + koff;
#pragma unroll
        for (int st = 0; st < 4; ++st) {
            bf16x8 b = *(const bf16x8*)(wrow + st * 32);
            acc = __builtin_amdgcn_mfma_f32_16x16x32_bf16(a[st], b, acc, 0, 0, 0);
        }
        float as_v = asrc[nt * 16 + col];
        float ad_v = adst[nt * 16 + col];
#pragma unroll
        for (int r = 0; r < 4; ++r) {
            int node = nodeb + r;
            if (node < N_NODES)
                h1b[(size_t)node * 128 + nt * 16 + col] = __float2bfloat16(acc[r]);
            float ps = acc[r] * as_v, pd = acc[r] * ad_v;
#pragma unroll
            for (int ofs = 1; ofs < 16; ofs <<= 1) {
                ps += __shfl_xor(ps, ofs, 64);
                pd += __shfl_xor(pd, ofs, 64);
            }
            if (col == 0 && node < N_NODES) {
                s1[node * 8 + nt] = ps;
                d1[node * 8 + nt] = pd;
            }
        }
    }
}

// ---------------- scan (degrees +1 for implicit self-loop) ------------------
__global__ __launch_bounds__(256) void k_scan_a(const int* __restrict__ deg,
                                                int* __restrict__ bsum) {
    __shared__ int red[256];
    int b = blockIdx.x, t = threadIdx.x;
    int base = b * SCAN_CHUNK + t * 4;
    int s = 0;
    if (base + 3 < N_NODES) {
        int4 v = *(const int4*)(deg + base);
        s = v.x + v.y + v.z + v.w + 4;
    } else {
#pragma unroll
        for (int i = 0; i < 4; ++i)
            if (base + i < N_NODES) s += deg[base + i] + 1;
    }
    red[t] = s;
    __syncthreads();
    for (int ofs = 128; ofs; ofs >>= 1) {
        if (t < ofs) red[t] += red[t + ofs];
        __syncthreads();
    }
    if (t == 0) bsum[b] = red[0];
}

__global__ void k_scan_b(const int* __restrict__ bsum, int* __restrict__ bpre) {
    int t = threadIdx.x;   // 64
    int a = (2 * t     < NBLK_SCAN) ? bsum[2 * t]     : 0;
    int b = (2 * t + 1 < NBLK_SCAN) ? bsum[2 * t + 1] : 0;
    int local = a + b;
    int incl = local;
#pragma unroll
    for (int ofs = 1; ofs < 64; ofs <<= 1) {
        int u = __shfl_up(incl, ofs, 64);
        if (t >= ofs) incl += u;
    }
    int pre = incl - local;
    if (2 * t     < NBLK_SCAN) bpre[2 * t]     = pre;
    if (2 * t + 1 < NBLK_SCAN) bpre[2 * t + 1] = pre + a;
}

__global__ __launch_bounds__(256) void k_scan_c(const int* __restrict__ deg,
                                                const int* __restrict__ bpre,
                                                int* __restrict__ off,
                                                int* __restrict__ cur,
                                                int* __restrict__ csr,
                                                int* __restrict__ gcur) {
    __shared__ int tsum[256];
    int b = blockIdx.x, t = threadIdx.x;
    int base = b * SCAN_CHUNK + t * 4;
    int d0 = 0, d1 = 0, d2 = 0, d3 = 0;
    if (base + 3 < N_NODES) {
        int4 v = *(const int4*)(deg + base);
        d0 = v.x + 1; d1 = v.y + 1; d2 = v.z + 1; d3 = v.w + 1;
    } else {
        if (base     < N_NODES) d0 = deg[base] + 1;
        if (base + 1 < N_NODES) d1 = deg[base + 1] + 1;
        if (base + 2 < N_NODES) d2 = deg[base + 2] + 1;
        if (base + 3 < N_NODES) d3 = deg[base + 3] + 1;
    }
    int s = d0 + d1 + d2 + d3;
    tsum[t] = s;
    __syncthreads();
    for (int ofs = 1; ofs < 256; ofs <<= 1) {
        int u = (t >= ofs) ? tsum[t - ofs] : 0;
        __syncthreads();
        tsum[t] += u;
        __syncthreads();
    }
    int run = bpre[b] + tsum[t] - s;
    if (base < N_NODES) {
        if ((base & 255) == 0) gcur[base >> SH] = run - base;
        off[base] = run; csr[run] = base; cur[base] = run + 1; run += d0;
    }
    if (base + 1 < N_NODES) { off[base + 1] = run; csr[run] = base + 1;
                              cur[base + 1] = run + 1; run += d1; }
    if (base + 2 < N_NODES) { off[base + 2] = run; csr[run] = base + 2;
                              cur[base + 2] = run + 1; run += d2; }
    if (base + 3 < N_NODES) { off[base + 3] = run; csr[run] = base + 3;
                              cur[base + 3] = run + 1; run += d3; }
    if (b == 0 && t == 0) off[N_NODES] = ETOT;
}

// ---------------- bin: bucket-major COO (standalone) ------------------------
__global__ __launch_bounds__(256) void k_bin(
    const int* __restrict__ src, const int* __restrict__ dst,
    int* __restrict__ gcur, int2* __restrict__ coo) {
    __shared__ int2 st[BIN_TILE];
    __shared__ int  hist[NBUCK + 1];
    __shared__ int  lstart[NBUCK];
    __shared__ int  gbase[NBUCK];
    __shared__ int  tsum[256];
    int wb = blockIdx.x, t = threadIdx.x;
    int e0 = wb * BIN_TILE;
    int nE = min(BIN_TILE, E_EDGES - e0);
    for (int i = t; i <= NBUCK; i += 256) hist[i] = 0;
    __syncthreads();
    for (int i = t; i < nE; i += 256)
        atomicAdd(&hist[dst[e0 + i] >> SH], 1);
    __syncthreads();
    int i0 = 2 * t, i1 = 2 * t + 1;
    int h0 = (i0 < NBUCK) ? hist[i0] : 0;
    int h1v = (i1 < NBUCK) ? hist[i1] : 0;
    int s = h0 + h1v;
    tsum[t] = s;
    __syncthreads();
    for (int ofs = 1; ofs < 256; ofs <<= 1) {
        int u = (t >= ofs) ? tsum[t - ofs] : 0;
        __syncthreads();
        tsum[t] += u;
        __syncthreads();
    }
    int pre = tsum[t] - s;
    if (i0 < NBUCK) hist[i0] = pre;
    if (i1 < NBUCK) hist[i1] = pre + h0;
    if (t == 255) hist[NBUCK] = tsum[255];
    __syncthreads();
    for (int i = t; i < NBUCK; i += 256) {
        int st_ = hist[i];
        int cnt = hist[i + 1] - st_;
        lstart[i] = st_;
        if (cnt > 0) gbase[i] = atomicAdd(&gcur[i], cnt);
    }
    __syncthreads();
    for (int i = t; i < nE; i += 256) {
        int sv = src[e0 + i], dv = dst[e0 + i];
        int p = atomicAdd(&hist[dv >> SH], 1);
        st[p] = make_int2(sv, dv);
    }
    __syncthreads();
    for (int i = t; i < nE; i += 256) {
        int2 e = st[i];
        int b2 = e.y >> SH;
        coo[gbase[b2] + (i - lstart[b2])] = e;
    }
}

// ---------------- fine: per-bucket LDS reorder (standalone) -----------------
__global__ __launch_bounds__(256) void k_fine(
    const int2* __restrict__ coo, const int* __restrict__ off,
    int* __restrict__ cur, int* __restrict__ csr) {
    __shared__ int lcur[256];
    __shared__ int lsrc[LDS_CAP];
    int b = blockIdx.x, t = threadIdx.x;
    int n0 = b << SH;
    int n1 = min(n0 + 256, N_NODES);
    int nn = n1 - n0;
    int base = off[n0], endv = off[n1];
    int ecnt = endv - base;
    int cooStart = base - n0;
    int cooEnd = endv - n1;
    if (ecnt <= LDS_CAP) {
        if (t < nn) {
            int o = off[n0 + t] - base;
            lcur[t] = o + 1;
            lsrc[o] = n0 + t;
        }
        __syncthreads();
        for (int i = cooStart + t; i < cooEnd; i += 256) {
            int2 e = coo[i];
            int p = atomicAdd(&lcur[e.y - n0], 1);
            lsrc[p] = e.x;
        }
        __syncthreads();
        for (int i = t; i < ecnt; i += 256)
            csr[base + i] = lsrc[i];
    } else {
        for (int i = cooStart + t; i < cooEnd; i += 256) {
            int2 e = coo[i];
            int slot = atomicAdd(&cur[e.y], 1);
            csr[slot] = e.x;
        }
    }
}

// ---------------- layer 1 single-pass softmax-aggregate (dot2 pairs) --------
__global__ __launch_bounds__(256) void k_l1(
    const int* __restrict__ off, const int* __restrict__ csr,
    const float* __restrict__ s1, const float* __restrict__ d1,
    const uint4* __restrict__ h1q, const float* __restrict__ b1,
    float* __restrict__ emb) {
    int t = threadIdx.x;
    int node = blockIdx.x * 4 + (t >> 6);
    int l = t & 63;
    int g = l >> 4, q = l & 15;
    int hb = q >> 1;
    int lo = off[node], hi = off[node + 1];
    float dvh = d1[node * 8 + hb];

    float acc[8];
#pragma unroll
    for (int c = 0; c < 8; ++c) acc[c] = 0.f;
    float den = 0.f;

    int idx = lo + g;
    while (idx + 4 < hi) {
        int sa = csr[idx], sb = csr[idx + 4];
        uint4 ba = h1q[(size_t)sa * 16 + q];
        uint4 bb = h1q[(size_t)sb * 16 + q];
        float w0 = __expf(lrelu(s1[sa * 8 + hb] + dvh));
        float w1 = __expf(lrelu(s1[sb * 8 + hb] + dvh));
        den += w0 + w1;
        unsigned int wp;
        asm("v_cvt_pk_bf16_f32 %0, %1, %2" : "=v"(wp) : "v"(w0), "v"(w1));
        unsigned int p0, p1;
        p0 = __builtin_amdgcn_perm(bb.x, ba.x, 0x05040100u);
        p1 = __builtin_amdgcn_perm(bb.x, ba.x, 0x07060302u);
        acc[0] = dot2bf(wp, p0, acc[0]);
        acc[1] = dot2bf(wp, p1, acc[1]);
        p0 = __builtin_amdgcn_perm(bb.y, ba.y, 0x05040100u);
        p1 = __builtin_amdgcn_perm(bb.y, ba.y, 0x07060302u);
        acc[2] = dot2bf(wp, p0, acc[2]);
        acc[3] = dot2bf(wp, p1, acc[3]);
        p0 = __builtin_amdgcn_perm(bb.z, ba.z, 0x05040100u);
        p1 = __builtin_amdgcn_perm(bb.z, ba.z, 0x07060302u);
        acc[4] = dot2bf(wp, p0, acc[4]);
        acc[5] = dot2bf(wp, p1, acc[5]);
        p0 = __builtin_amdgcn_perm(bb.w, ba.w, 0x05040100u);
        p1 = __builtin_amdgcn_perm(bb.w, ba.w, 0x07060302u);
        acc[6] = dot2bf(wp, p0, acc[6]);
        acc[7] = dot2bf(wp, p1, acc[7]);
        idx += 8;
    }
    if (idx < hi) {
        int sc = csr[idx];
        uint4 bv = h1q[(size_t)sc * 16 + q];
        float w = __expf(lrelu(s1[sc * 8 + hb] + dvh));
        den += w;
        acc[0] = fmaf(w, bflo(bv.x), acc[0]);
        acc[1] = fmaf(w, bfhi(bv.x), acc[1]);
        acc[2] = fmaf(w, bflo(bv.y), acc[2]);
        acc[3] = fmaf(w, bfhi(bv.y), acc[3]);
        acc[4] = fmaf(w, bflo(bv.z), acc[4]);
        acc[5] = fmaf(w, bfhi(bv.z), acc[5]);
        acc[6] = fmaf(w, bflo(bv.w), acc[6]);
        acc[7] = fmaf(w, bfhi(bv.w), acc[7]);
    }
#pragma unroll
    for (int c = 0; c < 8; ++c) {
        acc[c] += __shfl_xor(acc[c], 16, 64);
        acc[c] += __shfl_xor(acc[c], 32, 64);
    }
    den += __shfl_xor(den, 16, 64);
    den += __shfl_xor(den, 32, 64);

    if (l < 16) {
        float r = 1.f / den;
        float vv[8];
#pragma unroll
        for (int c = 0; c < 8; ++c) {
            float v = acc[c] * r + b1[8 * q + c];
            vv[c] = v > 0.f ? v : expm1f(v);
        }
        float4* ep = (float4*)(emb + (size_t)node * 128);
        ep[2 * q]     = make_float4(vv[0], vv[1], vv[2], vv[3]);
        ep[2 * q + 1] = make_float4(vv[4], vv[5], vv[6], vv[7]);
    }
}

// ---------------- layer 2 GEMM: h2(bf16) = emb @ W2 (128->16), s2/d2 --------
__global__ __launch_bounds__(256) void k_gemm2(
    const float* __restrict__ emb, const float* __restrict__ W,
    const float* __restrict__ asrc, const float* __restrict__ adst,
    __hip_bfloat16* __restrict__ h2b, float* __restrict__ s2,
    float* __restrict__ d2) {
    __shared__ float xs[16][129];
    int n0 = blockIdx.x * 16;
    int t = threadIdx.x;
#pragma unroll
    for (int i = 0; i < 8; ++i) {
        int idx = t + i * 256;
        xs[idx >> 7][idx & 127] = emb[(long)n0 * 128 + idx];
    }
    __syncthreads();
    int j = t & 15, sub = t >> 4;
    float acc = 0.f;
    for (int k = 0; k < 128; ++k) acc = fmaf(xs[sub][k], W[k * 16 + j], acc);
    int n = n0 + sub;
    h2b[(long)n * 16 + j] = __float2bfloat16(acc);
    float ps = acc * asrc[j], pd = acc * adst[j];
#pragma unroll
    for (int off = 8; off; off >>= 1) {
        ps += __shfl_down(ps, off, 16);
        pd += __shfl_down(pd, off, 16);
    }
    if (j == 0) { s2[n] = ps; d2[n] = pd; }
}

// ---------------- layer 2 single-pass aggregate + log_softmax ---------------
__global__ __launch_bounds__(256) void k_l2(
    const int* __restrict__ off, const int* __restrict__ csr,
    const float* __restrict__ s2, const float* __restrict__ d2,
    const unsigned int* __restrict__ h2w, const float* __restrict__ b2,
    float* __restrict__ logits) {
    int t = threadIdx.x;
    int node = blockIdx.x * 4 + (t >> 6);
    int l = t & 63;
    int g = l >> 3, p = l & 7;
    int lo = off[node], hi = off[node + 1];
    float dv = d2[node];

    float ax = 0.f, ay = 0.f, den = 0.f;
    for (int idx = lo + g; idx < hi; idx += 8) {
        int s = csr[idx];
        float w = __expf(lrelu(s2[s] + dv));
        den += w;
        unsigned int bv = h2w[(size_t)s * 8 + p];
        ax = fmaf(w, bflo(bv), ax);
        ay = fmaf(w, bfhi(bv), ay);
    }
#pragma unroll
    for (int ofs = 8; ofs < 64; ofs <<= 1) {
        ax += __shfl_xor(ax, ofs, 64);
        ay += __shfl_xor(ay, ofs, 64);
        den += __shfl_xor(den, ofs, 64);
    }
    float r = 1.f / den;
    float v0 = ax * r + b2[2 * p], v1 = ay * r + b2[2 * p + 1];
    float mm = fmaxf(v0, v1);
#pragma unroll
    for (int ofs = 1; ofs < 8; ofs <<= 1) mm = fmaxf(mm, __shfl_xor(mm, ofs, 8));
    float sm = __expf(v0 - mm) + __expf(v1 - mm);
#pragma unroll
    for (int ofs = 1; ofs < 8; ofs <<= 1) sm += __shfl_xor(sm, ofs, 8);
    if (g == 0) {
        float ls = logf(sm);
        logits[node * 16 + 2 * p]     = v0 - mm - ls;
        logits[node * 16 + 2 * p + 1] = v1 - mm - ls;
    }
}

extern "C" void kernel_launch(void* const* d_in, const int* in_sizes, int n_in,
                              void* d_out, int out_size, void* d_ws, size_t ws_size,
                              hipStream_t stream) {
    const float* x   = (const float*)d_in[0];
    const int*   ei  = (const int*)d_in[1];
    const float* W1  = (const float*)d_in[2];
    const float* as1 = (const float*)d_in[3];
    const float* ad1 = (const float*)d_in[4];
    const float* b1  = (const float*)d_in[5];
    const float* W2  = (const float*)d_in[6];
    const float* as2 = (const float*)d_in[7];
    const float* ad2 = (const float*)d_in[8];
    const float* b2  = (const float*)d_in[9];

    float* out    = (float*)d_out;
    float* logits = out;                          // [N,16]
    float* emb    = out + (size_t)N_NODES * 16;   // [N,128]

    float* ws    = (float*)d_ws;
    unsigned int* h1w = (unsigned int*)ws;                    // N*64 words (bf16 x2)
    float* s1    = (float*)(h1w + (size_t)N_NODES * 64);      // N*8
    float* d1    = s1 + (size_t)N_NODES * 8;
    unsigned int* h2w = (unsigned int*)(d1 + (size_t)N_NODES * 8); // N*8 words
    float* s2    = (float*)(h2w + (size_t)N_NODES * 8);       // N
    float* d2v   = s2 + (size_t)N_NODES;
    int*   deg   = (int*)(d2v + (size_t)N_NODES);             // N
    int*   offs  = deg + N_NODES;                             // N+1
    int*   cur   = offs + N_NODES + 1;                        // N
    int*   csr   = cur + N_NODES;                             // ETOT
    int*   bsum  = csr + ETOT;                                // NBLK_SCAN
    int*   bpre  = bsum + NBLK_SCAN;                          // NBLK_SCAN
    int*   gcur  = bpre + NBLK_SCAN;                          // NBUCK
    int2*  coo   = (int2*)(gcur + NBUCK + 1);                 // E_EDGES pairs
    unsigned short* wtg = (unsigned short*)(coo + E_EDGES);   // 128*128 bf16

    const int* srcp = ei;
    const int* dstp = ei + E_EDGES;

    hipMemsetAsync(deg, 0, (size_t)N_NODES * sizeof(int), stream);

    k_wt<<<64, 256, 0, stream>>>(W1, wtg);
    k_parA<<<NHIST + NMFMA, 256, 0, stream>>>(dstp, deg, x, wtg, as1, ad1,
                                              (__hip_bfloat16*)h1w, s1, d1);
    k_scan_a<<<NBLK_SCAN, 256, 0, stream>>>(deg, bsum);
    k_scan_b<<<1, 64, 0, stream>>>(bsum, bpre);
    k_scan_c<<<NBLK_SCAN, 256, 0, stream>>>(deg, bpre, offs, cur, csr, gcur);
    k_bin<<<NBIN, 256, 0, stream>>>(srcp, dstp, gcur, coo);
    k_fine<<<NBUCK, 256, 0, stream>>>(coo, offs, cur, csr);

    k_l1<<<N_NODES / 4, 256, 0, stream>>>(offs, csr, s1, d1,
                                          (const uint4*)h1w, b1, emb);

    k_gemm2<<<N_NODES / 16, 256, 0, stream>>>(emb, W2, as2, ad2,
                                              (__hip_bfloat16*)h2w, s2, d2v);
    k_l2<<<N_NODES / 4, 256, 0, stream>>>(offs, csr, s2, d2v, h2w, b2, logits);
}

// Round 16
// 266.202 us; speedup vs baseline: 1.1975x; 1.1975x over previous
//
#include <hip/hip_runtime.h>
#include <hip/hip_bf16.h>
#include <math.h>

#define N_NODES 100000
#define E_EDGES 1600000
#define ETOT    (E_EDGES + N_NODES)
#define NEG     0.2f

// bucketed CSR build
#define SH        8
#define NBUCK     ((N_NODES + 255) >> 8)          // 391
#define BIN_TILE  4096
#define NBIN      ((E_EDGES + BIN_TILE - 1) / BIN_TILE)  // 391
#define CAP_B     5120                            // per-bucket COO capacity (+16 sigma)

#define NMFMA     ((N_NODES + 63) / 64)           // 1563

typedef __attribute__((ext_vector_type(8))) short bf16x8;
typedef __attribute__((ext_vector_type(4))) float f32x4;
typedef __attribute__((ext_vector_type(2))) short bf16p;

__device__ inline float lrelu(float x) { return x > 0.f ? x : NEG * x; }
__device__ inline float bflo(unsigned int b) { return __uint_as_float(b << 16); }
__device__ inline float bfhi(unsigned int b) { return __uint_as_float(b & 0xFFFF0000u); }
__device__ inline unsigned short f2bf(float f) {   // RNE bf16 bits
    unsigned int u = __float_as_uint(f);
    return (unsigned short)((u + 0x7FFFu + ((u >> 16) & 1u)) >> 16);
}

// dot of 2 bf16 pairs with f32 accumulate
__device__ inline float dot2bf(unsigned int wp, unsigned int hp, float c) {
#if __has_builtin(__builtin_amdgcn_fdot2_f32_bf16)
    return __builtin_amdgcn_fdot2_f32_bf16(__builtin_bit_cast(bf16p, wp),
                                           __builtin_bit_cast(bf16p, hp),
                                           c, false);
#else
    return fmaf(bflo(wp), bflo(hp), fmaf(bfhi(wp), bfhi(hp), c));
#endif
}

// ---------------- W1^T -> bf16 (one-off, 32 KB) -----------------------------
__global__ __launch_bounds__(256) void k_wt(const float* __restrict__ W,
                                            unsigned short* __restrict__ wtg) {
    int t = blockIdx.x * 256 + threadIdx.x;   // t = n*128 + k
    if (t >= 128 * 128) return;
    int n = t >> 7, k = t & 127;
    wtg[t] = f2bf(W[k * 128 + n]);
}

// ---------------- MFMA gemm1 (bf16, W^T from global), standalone ------------
__global__ __launch_bounds__(256) void k_gemm1(
    const float* __restrict__ x, const unsigned short* __restrict__ wtg,
    const float* __restrict__ asrc, const float* __restrict__ adst,
    __hip_bfloat16* __restrict__ h1b, float* __restrict__ s1,
    float* __restrict__ d1) {
    __shared__ unsigned short xb[64][136];
    int t = threadIdx.x;
    int n0 = blockIdx.x * 64;

    // stage x tile (64x128 fp32 -> bf16), float4 coalesced, 2-way LDS writes
#pragma unroll
    for (int i = 0; i < 8; ++i) {
        int i4 = t + i * 256;
        int r = i4 >> 5;
        int c = (i4 & 31) * 4;
        float4 v = make_float4(0.f, 0.f, 0.f, 0.f);
        if (n0 + r < N_NODES) v = *(const float4*)(x + (size_t)(n0 + r) * 128 + c);
        xb[r][c + 0] = f2bf(v.x);
        xb[r][c + 1] = f2bf(v.y);
        xb[r][c + 2] = f2bf(v.z);
        xb[r][c + 3] = f2bf(v.w);
    }
    __syncthreads();

    int l = t & 63, wv = t >> 6;
    int col = l & 15, q4 = l >> 4;
    int rbase = wv * 16;
    int koff = q4 * 8;

    bf16x8 a[4];
#pragma unroll
    for (int st = 0; st < 4; ++st)
        a[st] = *(const bf16x8*)&xb[rbase + col][st * 32 + koff];

    int nodeb = n0 + rbase + q4 * 4;
#pragma unroll
    for (int nt = 0; nt < 8; ++nt) {
        f32x4 acc = {0.f, 0.f, 0.f, 0.f};
        const unsigned short* wrow = wtg + (size_t)(nt * 16 + col) * 128 + koff;
#pragma unroll
        for (int st = 0; st < 4; ++st) {
            bf16x8 b = *(const bf16x8*)(wrow + st * 32);
            acc = __builtin_amdgcn_mfma_f32_16x16x32_bf16(a[st], b, acc, 0, 0, 0);
        }
        float as_v = asrc[nt * 16 + col];
        float ad_v = adst[nt * 16 + col];
#pragma unroll
        for (int r = 0; r < 4; ++r) {
            int node = nodeb + r;
            if (node < N_NODES)
                h1b[(size_t)node * 128 + nt * 16 + col] = __float2bfloat16(acc[r]);
            float ps = acc[r] * as_v, pd = acc[r] * ad_v;
#pragma unroll
            for (int ofs = 1; ofs < 16; ofs <<= 1) {
                ps += __shfl_xor(ps, ofs, 64);
                pd += __shfl_xor(pd, ofs, 64);
            }
            if (col == 0 && node < N_NODES) {
                s1[node * 8 + nt] = ps;
                d1[node * 8 + nt] = pd;
            }
        }
    }
}

// ---------------- bin: bucket-major COO into fixed segments -----------------
__global__ __launch_bounds__(256) void k_bin(
    const int* __restrict__ src, const int* __restrict__ dst,
    int* __restrict__ gcur, int2* __restrict__ coo) {
    __shared__ int2 st[BIN_TILE];
    __shared__ int  hist[NBUCK + 1];
    __shared__ int  lstart[NBUCK];
    __shared__ int  gbase[NBUCK];
    __shared__ int  tsum[256];
    int wb = blockIdx.x, t = threadIdx.x;
    int e0 = wb * BIN_TILE;
    int nE = min(BIN_TILE, E_EDGES - e0);
    for (int i = t; i <= NBUCK; i += 256) hist[i] = 0;
    __syncthreads();
    for (int i = t; i < nE; i += 256)
        atomicAdd(&hist[dst[e0 + i] >> SH], 1);
    __syncthreads();
    int i0 = 2 * t, i1 = 2 * t + 1;
    int h0 = (i0 < NBUCK) ? hist[i0] : 0;
    int h1v = (i1 < NBUCK) ? hist[i1] : 0;
    int s = h0 + h1v;
    tsum[t] = s;
    __syncthreads();
    for (int ofs = 1; ofs < 256; ofs <<= 1) {
        int u = (t >= ofs) ? tsum[t - ofs] : 0;
        __syncthreads();
        tsum[t] += u;
        __syncthreads();
    }
    int pre = tsum[t] - s;
    if (i0 < NBUCK) hist[i0] = pre;
    if (i1 < NBUCK) hist[i1] = pre + h0;
    if (t == 255) hist[NBUCK] = tsum[255];
    __syncthreads();
    for (int i = t; i < NBUCK; i += 256) {
        int st_ = hist[i];
        int cnt = hist[i + 1] - st_;
        lstart[i] = st_;
        if (cnt > 0) gbase[i] = i * CAP_B + atomicAdd(&gcur[i], cnt);
    }
    __syncthreads();
    for (int i = t; i < nE; i += 256) {
        int sv = src[e0 + i], dv = dst[e0 + i];
        int p = atomicAdd(&hist[dv >> SH], 1);
        st[p] = make_int2(sv, dv);
    }
    __syncthreads();
    for (int i = t; i < nE; i += 256) {
        int2 e = st[i];
        int b2 = e.y >> SH;
        int slot = gbase[b2] + (i - lstart[b2]);
        slot = min(slot, (b2 + 1) * CAP_B - 1);   // overflow clamp (never in practice)
        coo[slot] = e;
    }
}

// ---------------- scanb: 391 bucket totals -> bbase; off[N]=ETOT ------------
__global__ __launch_bounds__(256) void k_scanb(const int* __restrict__ gcur,
                                               int* __restrict__ bbase,
                                               int* __restrict__ off) {
    __shared__ int tsum[256];
    int t = threadIdx.x;
    int i0 = 2 * t, i1 = 2 * t + 1;
    int a = 0, b = 0;
    if (i0 < NBUCK) a = min(gcur[i0], CAP_B) + min(256, N_NODES - (i0 << SH));
    if (i1 < NBUCK) b = min(gcur[i1], CAP_B) + min(256, N_NODES - (i1 << SH));
    int s = a + b;
    tsum[t] = s;
    __syncthreads();
    for (int ofs = 1; ofs < 256; ofs <<= 1) {
        int u = (t >= ofs) ? tsum[t - ofs] : 0;
        __syncthreads();
        tsum[t] += u;
        __syncthreads();
    }
    int pre = tsum[t] - s;
    if (i0 < NBUCK) bbase[i0] = pre;
    if (i1 < NBUCK) bbase[i1] = pre + a;
    if (t == 0) off[N_NODES] = ETOT;
}

// ---------------- fine: per-bucket LDS hist+scan+reorder -> off, csr --------
__global__ __launch_bounds__(256) void k_fine(
    const int2* __restrict__ coo, const int* __restrict__ gcur,
    const int* __restrict__ bbase, int* __restrict__ off,
    int* __restrict__ csr) {
    __shared__ int ldeg[256];           // histogram, then per-node cursor
    __shared__ int lpre[256];
    __shared__ int lsrc[CAP_B + 256];
    int b = blockIdx.x, t = threadIdx.x;
    int n0 = b << SH;
    int nn = min(256, N_NODES - n0);
    int ecnt = min(gcur[b], CAP_B);
    int base = bbase[b];
    const int2* seg = coo + (size_t)b * CAP_B;

    ldeg[t] = 0;
    __syncthreads();
    for (int i = t; i < ecnt; i += 256)
        atomicAdd(&ldeg[seg[i].y - n0], 1);
    __syncthreads();
    int d = (t < nn) ? ldeg[t] + 1 : 0;   // +1 self-loop
    lpre[t] = d;
    __syncthreads();
    for (int ofs = 1; ofs < 256; ofs <<= 1) {
        int u = (t >= ofs) ? lpre[t - ofs] : 0;
        __syncthreads();
        lpre[t] += u;
        __syncthreads();
    }
    int myoff = lpre[t] - d;              // local exclusive prefix
    __syncthreads();
    if (t < nn) {
        off[n0 + t] = base + myoff;
        lsrc[myoff] = n0 + t;             // self-loop in slot 0
        ldeg[t] = myoff + 1;              // cursor
    }
    __syncthreads();
    for (int i = t; i < ecnt; i += 256) {
        int2 e = seg[i];
        int p = atomicAdd(&ldeg[e.y - n0], 1);
        lsrc[p] = e.x;
    }
    __syncthreads();
    int tot = ecnt + nn;
    for (int i = t; i < tot; i += 256)
        csr[base + i] = lsrc[i];
}

// ---------------- layer 1 single-pass softmax-aggregate (dot2 pairs) --------
__global__ __launch_bounds__(256) void k_l1(
    const int* __restrict__ off, const int* __restrict__ csr,
    const float* __restrict__ s1, const float* __restrict__ d1,
    const uint4* __restrict__ h1q, const float* __restrict__ b1,
    float* __restrict__ emb) {
    int t = threadIdx.x;
    int node = blockIdx.x * 4 + (t >> 6);
    int l = t & 63;
    int g = l >> 4, q = l & 15;
    int hb = q >> 1;
    int lo = off[node], hi = off[node + 1];
    float dvh = d1[node * 8 + hb];

    float acc[8];
#pragma unroll
    for (int c = 0; c < 8; ++c) acc[c] = 0.f;
    float den = 0.f;

    int idx = lo + g;
    while (idx + 4 < hi) {
        int sa = csr[idx], sb = csr[idx + 4];
        uint4 ba = h1q[(size_t)sa * 16 + q];
        uint4 bb = h1q[(size_t)sb * 16 + q];
        float w0 = __expf(lrelu(s1[sa * 8 + hb] + dvh));
        float w1 = __expf(lrelu(s1[sb * 8 + hb] + dvh));
        den += w0 + w1;
        unsigned int wp;
        asm("v_cvt_pk_bf16_f32 %0, %1, %2" : "=v"(wp) : "v"(w0), "v"(w1));
        unsigned int p0, p1;
        p0 = __builtin_amdgcn_perm(bb.x, ba.x, 0x05040100u);
        p1 = __builtin_amdgcn_perm(bb.x, ba.x, 0x07060302u);
        acc[0] = dot2bf(wp, p0, acc[0]);
        acc[1] = dot2bf(wp, p1, acc[1]);
        p0 = __builtin_amdgcn_perm(bb.y, ba.y, 0x05040100u);
        p1 = __builtin_amdgcn_perm(bb.y, ba.y, 0x07060302u);
        acc[2] = dot2bf(wp, p0, acc[2]);
        acc[3] = dot2bf(wp, p1, acc[3]);
        p0 = __builtin_amdgcn_perm(bb.z, ba.z, 0x05040100u);
        p1 = __builtin_amdgcn_perm(bb.z, ba.z, 0x07060302u);
        acc[4] = dot2bf(wp, p0, acc[4]);
        acc[5] = dot2bf(wp, p1, acc[5]);
        p0 = __builtin_amdgcn_perm(bb.w, ba.w, 0x05040100u);
        p1 = __builtin_amdgcn_perm(bb.w, ba.w, 0x07060302u);
        acc[6] = dot2bf(wp, p0, acc[6]);
        acc[7] = dot2bf(wp, p1, acc[7]);
        idx += 8;
    }
    if (idx < hi) {
        int sc = csr[idx];
        uint4 bv = h1q[(size_t)sc * 16 + q];
        float w = __expf(lrelu(s1[sc * 8 + hb] + dvh));
        den += w;
        acc[0] = fmaf(w, bflo(bv.x), acc[0]);
        acc[1] = fmaf(w, bfhi(bv.x), acc[1]);
        acc[2] = fmaf(w, bflo(bv.y), acc[2]);
        acc[3] = fmaf(w, bfhi(bv.y), acc[3]);
        acc[4] = fmaf(w, bflo(bv.z), acc[4]);
        acc[5] = fmaf(w, bfhi(bv.z), acc[5]);
        acc[6] = fmaf(w, bflo(bv.w), acc[6]);
        acc[7] = fmaf(w, bfhi(bv.w), acc[7]);
    }
#pragma unroll
    for (int c = 0; c < 8; ++c) {
        acc[c] += __shfl_xor(acc[c], 16, 64);
        acc[c] += __shfl_xor(acc[c], 32, 64);
    }
    den += __shfl_xor(den, 16, 64);
    den += __shfl_xor(den, 32, 64);

    if (l < 16) {
        float r = 1.f / den;
        float vv[8];
#pragma unroll
        for (int c = 0; c < 8; ++c) {
            float v = acc[c] * r + b1[8 * q + c];
            vv[c] = v > 0.f ? v : expm1f(v);
        }
        float4* ep = (float4*)(emb + (size_t)node * 128);
        ep[2 * q]     = make_float4(vv[0], vv[1], vv[2], vv[3]);
        ep[2 * q + 1] = make_float4(vv[4], vv[5], vv[6], vv[7]);
    }
}

// ---------------- layer 2 GEMM: h2(bf16) = emb @ W2 (128->16), s2/d2 --------
__global__ __launch_bounds__(256) void k_gemm2(
    const float* __restrict__ emb, const float* __restrict__ W,
    const float* __restrict__ asrc, const float* __restrict__ adst,
    __hip_bfloat16* __restrict__ h2b, float* __restrict__ s2,
    float* __restrict__ d2) {
    __shared__ float xs[16][129];
    int n0 = blockIdx.x * 16;
    int t = threadIdx.x;
#pragma unroll
    for (int i = 0; i < 8; ++i) {
        int idx = t + i * 256;
        xs[idx >> 7][idx & 127] = emb[(long)n0 * 128 + idx];
    }
    __syncthreads();
    int j = t & 15, sub = t >> 4;
    float acc = 0.f;
    for (int k = 0; k < 128; ++k) acc = fmaf(xs[sub][k], W[k * 16 + j], acc);
    int n = n0 + sub;
    h2b[(long)n * 16 + j] = __float2bfloat16(acc);
    float ps = acc * asrc[j], pd = acc * adst[j];
#pragma unroll
    for (int off = 8; off; off >>= 1) {
        ps += __shfl_down(ps, off, 16);
        pd += __shfl_down(pd, off, 16);
    }
    if (j == 0) { s2[n] = ps; d2[n] = pd; }
}

// ---------------- layer 2 single-pass aggregate + log_softmax ---------------
__global__ __launch_bounds__(256) void k_l2(
    const int* __restrict__ off, const int* __restrict__ csr,
    const float* __restrict__ s2, const float* __restrict__ d2,
    const unsigned int* __restrict__ h2w, const float* __restrict__ b2,
    float* __restrict__ logits) {
    int t = threadIdx.x;
    int node = blockIdx.x * 4 + (t >> 6);
    int l = t & 63;
    int g = l >> 3, p = l & 7;
    int lo = off[node], hi = off[node + 1];
    float dv = d2[node];

    float ax = 0.f, ay = 0.f, den = 0.f;
    for (int idx = lo + g; idx < hi; idx += 8) {
        int s = csr[idx];
        float w = __expf(lrelu(s2[s] + dv));
        den += w;
        unsigned int bv = h2w[(size_t)s * 8 + p];
        ax = fmaf(w, bflo(bv), ax);
        ay = fmaf(w, bfhi(bv), ay);
    }
#pragma unroll
    for (int ofs = 8; ofs < 64; ofs <<= 1) {
        ax += __shfl_xor(ax, ofs, 64);
        ay += __shfl_xor(ay, ofs, 64);
        den += __shfl_xor(den, ofs, 64);
    }
    float r = 1.f / den;
    float v0 = ax * r + b2[2 * p], v1 = ay * r + b2[2 * p + 1];
    float mm = fmaxf(v0, v1);
#pragma unroll
    for (int ofs = 1; ofs < 8; ofs <<= 1) mm = fmaxf(mm, __shfl_xor(mm, ofs, 8));
    float sm = __expf(v0 - mm) + __expf(v1 - mm);
#pragma unroll
    for (int ofs = 1; ofs < 8; ofs <<= 1) sm += __shfl_xor(sm, ofs, 8);
    if (g == 0) {
        float ls = logf(sm);
        logits[node * 16 + 2 * p]     = v0 - mm - ls;
        logits[node * 16 + 2 * p + 1] = v1 - mm - ls;
    }
}

extern "C" void kernel_launch(void* const* d_in, const int* in_sizes, int n_in,
                              void* d_out, int out_size, void* d_ws, size_t ws_size,
                              hipStream_t stream) {
    const float* x   = (const float*)d_in[0];
    const int*   ei  = (const int*)d_in[1];
    const float* W1  = (const float*)d_in[2];
    const float* as1 = (const float*)d_in[3];
    const float* ad1 = (const float*)d_in[4];
    const float* b1  = (const float*)d_in[5];
    const float* W2  = (const float*)d_in[6];
    const float* as2 = (const float*)d_in[7];
    const float* ad2 = (const float*)d_in[8];
    const float* b2  = (const float*)d_in[9];

    float* out    = (float*)d_out;
    float* logits = out;                          // [N,16]
    float* emb    = out + (size_t)N_NODES * 16;   // [N,128]

    float* ws    = (float*)d_ws;
    unsigned int* h1w = (unsigned int*)ws;                    // N*64 words (bf16 x2)
    int2*  coo   = (int2*)(h1w + (size_t)N_NODES * 64);      // NBUCK*CAP_B (8B-aligned)
    float* s1    = (float*)(coo + (size_t)NBUCK * CAP_B);     // N*8
    float* d1    = s1 + (size_t)N_NODES * 8;
    unsigned int* h2w = (unsigned int*)(d1 + (size_t)N_NODES * 8); // N*8 words
    float* s2    = (float*)(h2w + (size_t)N_NODES * 8);       // N
    float* d2v   = s2 + (size_t)N_NODES;
    int*   offs  = (int*)(d2v + (size_t)N_NODES);             // N+1
    int*   csr   = offs + N_NODES + 2;                        // ETOT
    int*   gcur  = csr + ETOT;                                // NBUCK
    int*   bbase = gcur + NBUCK;                              // NBUCK
    unsigned short* wtg = (unsigned short*)(bbase + NBUCK);   // 128*128 bf16

    const int* srcp = ei;
    const int* dstp = ei + E_EDGES;

    hipMemsetAsync(gcur, 0, (size_t)NBUCK * sizeof(int), stream);

    k_wt<<<64, 256, 0, stream>>>(W1, wtg);
    k_gemm1<<<NMFMA, 256, 0, stream>>>(x, wtg, as1, ad1,
                                       (__hip_bfloat16*)h1w, s1, d1);
    k_bin<<<NBIN, 256, 0, stream>>>(srcp, dstp, gcur, coo);
    k_scanb<<<1, 256, 0, stream>>>(gcur, bbase, offs);
    k_fine<<<NBUCK, 256, 0, stream>>>(coo, gcur, bbase, offs, csr);

    k_l1<<<N_NODES / 4, 256, 0, stream>>>(offs, csr, s1, d1,
                                          (const uint4*)h1w, b1, emb);

    k_gemm2<<<N_NODES / 16, 256, 0, stream>>>(emb, W2, as2, ad2,
                                              (__hip_bfloat16*)h2w, s2, d2v);
    k_l2<<<N_NODES / 4, 256, 0, stream>>>(offs, csr, s2, d2v, h2w, b2, logits);
}

// Round 17
// 259.342 us; speedup vs baseline: 1.2292x; 1.0265x over previous
//
#include <hip/hip_runtime.h>
#include <hip/hip_bf16.h>
#include <math.h>

#define N_NODES 100000
#define E_EDGES 1600000
#define ETOT    (E_EDGES + N_NODES)
#define NEG     0.2f

// bucketed CSR build
#define SH        8
#define NBUCK     ((N_NODES + 255) >> 8)          // 391
#define BIN_TILE  2048
#define NBIN      ((E_EDGES + BIN_TILE - 1) / BIN_TILE)  // 782
#define CAP_B     5120                            // per-bucket COO capacity

#define NMFMA     ((N_NODES + 63) / 64)           // 1563
#define G_A       782                             // gemm blocks fused with bin
#define G_B       (NMFMA - G_A)                   // 781, fused with fine

typedef __attribute__((ext_vector_type(8))) short bf16x8;
typedef __attribute__((ext_vector_type(4))) float f32x4;
typedef __attribute__((ext_vector_type(2))) short bf16p;

__device__ inline float lrelu(float x) { return x > 0.f ? x : NEG * x; }
__device__ inline float bflo(unsigned int b) { return __uint_as_float(b << 16); }
__device__ inline float bfhi(unsigned int b) { return __uint_as_float(b & 0xFFFF0000u); }
__device__ inline unsigned short f2bf(float f) {   // RNE bf16 bits
    unsigned int u = __float_as_uint(f);
    return (unsigned short)((u + 0x7FFFu + ((u >> 16) & 1u)) >> 16);
}

// dot of 2 bf16 pairs with f32 accumulate
__device__ inline float dot2bf(unsigned int wp, unsigned int hp, float c) {
#if __has_builtin(__builtin_amdgcn_fdot2_f32_bf16)
    return __builtin_amdgcn_fdot2_f32_bf16(__builtin_bit_cast(bf16p, wp),
                                           __builtin_bit_cast(bf16p, hp),
                                           c, false);
#else
    return fmaf(bflo(wp), bflo(hp), fmaf(bfhi(wp), bfhi(hp), c));
#endif
}

// ---------------- W1^T -> bf16 (one-off, 32 KB) -----------------------------
__global__ __launch_bounds__(256) void k_wt(const float* __restrict__ W,
                                            unsigned short* __restrict__ wtg) {
    int t = blockIdx.x * 256 + threadIdx.x;   // t = n*128 + k
    if (t >= 128 * 128) return;
    int n = t >> 7, k = t & 127;
    wtg[t] = f2bf(W[k * 128 + n]);
}

// ---------------- gemm1 role (device fn): 64 nodes per block ----------------
__device__ __forceinline__ void gemm1_role(
    int n0, int t, unsigned short (*xb)[136],
    const float* __restrict__ x, const unsigned short* __restrict__ wtg,
    const float* __restrict__ asrc, const float* __restrict__ adst,
    __hip_bfloat16* __restrict__ h1b, float* __restrict__ s1,
    float* __restrict__ d1) {
#pragma unroll
    for (int i = 0; i < 8; ++i) {
        int i4 = t + i * 256;
        int r = i4 >> 5;
        int c = (i4 & 31) * 4;
        float4 v = make_float4(0.f, 0.f, 0.f, 0.f);
        if (n0 + r < N_NODES) v = *(const float4*)(x + (size_t)(n0 + r) * 128 + c);
        xb[r][c + 0] = f2bf(v.x);
        xb[r][c + 1] = f2bf(v.y);
        xb[r][c + 2] = f2bf(v.z);
        xb[r][c + 3] = f2bf(v.w);
    }
    __syncthreads();

    int l = t & 63, wv = t >> 6;
    int col = l & 15, q4 = l >> 4;
    int rbase = wv * 16;
    int koff = q4 * 8;

    bf16x8 a[4];
#pragma unroll
    for (int st = 0; st < 4; ++st)
        a[st] = *(const bf16x8*)&xb[rbase + col][st * 32 + koff];

    int nodeb = n0 + rbase + q4 * 4;
#pragma unroll
    for (int nt = 0; nt < 8; ++nt) {
        f32x4 acc = {0.f, 0.f, 0.f, 0.f};
        const unsigned short* wrow = wtg + (size_t)(nt * 16 + col) * 128 + koff;
#pragma unroll
        for (int st = 0; st < 4; ++st) {
            bf16x8 b = *(const bf16x8*)(wrow + st * 32);
            acc = __builtin_amdgcn_mfma_f32_16x16x32_bf16(a[st], b, acc, 0, 0, 0);
        }
        float as_v = asrc[nt * 16 + col];
        float ad_v = adst[nt * 16 + col];
#pragma unroll
        for (int r = 0; r < 4; ++r) {
            int node = nodeb + r;
            if (node < N_NODES)
                h1b[(size_t)node * 128 + nt * 16 + col] = __float2bfloat16(acc[r]);
            float ps = acc[r] * as_v, pd = acc[r] * ad_v;
#pragma unroll
            for (int ofs = 1; ofs < 16; ofs <<= 1) {
                ps += __shfl_xor(ps, ofs, 64);
                pd += __shfl_xor(pd, ofs, 64);
            }
            if (col == 0 && node < N_NODES) {
                s1[node * 8 + nt] = ps;
                d1[node * 8 + nt] = pd;
            }
        }
    }
}

// ---------------- kernel: bin (bucket-major COO) || gemm1 part A ------------
union SmemBin {
    struct {
        int2 st[BIN_TILE];
        int  hist[NBUCK + 1];
        int  lstart[NBUCK];
        int  gbase[NBUCK];
        int  tsum[256];
    } b;
    unsigned short xb[64][136];
};

__global__ __launch_bounds__(256) void k_parBin(
    const int* __restrict__ src, const int* __restrict__ dst,
    int* __restrict__ gcur, int2* __restrict__ coo,
    const float* __restrict__ x, const unsigned short* __restrict__ wtg,
    const float* __restrict__ asrc, const float* __restrict__ adst,
    __hip_bfloat16* __restrict__ h1b, float* __restrict__ s1,
    float* __restrict__ d1) {
    __shared__ SmemBin sm;
    int bid = blockIdx.x, t = threadIdx.x;
    if (bid & 1) {                      // gemm role, gid 0..G_A-1
        gemm1_role((bid >> 1) * 64, t, sm.xb, x, wtg, asrc, adst, h1b, s1, d1);
        return;
    }
    int wb = bid >> 1;                  // bin tile 0..NBIN-1
    int e0 = wb * BIN_TILE;
    int nE = min(BIN_TILE, E_EDGES - e0);
    for (int i = t; i <= NBUCK; i += 256) sm.b.hist[i] = 0;
    __syncthreads();
    for (int i = t; i < nE; i += 256)
        atomicAdd(&sm.b.hist[dst[e0 + i] >> SH], 1);
    __syncthreads();
    int i0 = 2 * t, i1 = 2 * t + 1;
    int h0 = (i0 < NBUCK) ? sm.b.hist[i0] : 0;
    int h1v = (i1 < NBUCK) ? sm.b.hist[i1] : 0;
    int s = h0 + h1v;
    sm.b.tsum[t] = s;
    __syncthreads();
    for (int ofs = 1; ofs < 256; ofs <<= 1) {
        int u = (t >= ofs) ? sm.b.tsum[t - ofs] : 0;
        __syncthreads();
        sm.b.tsum[t] += u;
        __syncthreads();
    }
    int pre = sm.b.tsum[t] - s;
    if (i0 < NBUCK) sm.b.hist[i0] = pre;
    if (i1 < NBUCK) sm.b.hist[i1] = pre + h0;
    if (t == 255) sm.b.hist[NBUCK] = sm.b.tsum[255];
    __syncthreads();
    for (int i = t; i < NBUCK; i += 256) {
        int st_ = sm.b.hist[i];
        int cnt = sm.b.hist[i + 1] - st_;
        sm.b.lstart[i] = st_;
        if (cnt > 0) sm.b.gbase[i] = i * CAP_B + atomicAdd(&gcur[i], cnt);
    }
    __syncthreads();
    for (int i = t; i < nE; i += 256) {
        int sv = src[e0 + i], dv = dst[e0 + i];
        int p = atomicAdd(&sm.b.hist[dv >> SH], 1);
        sm.b.st[p] = make_int2(sv, dv);
    }
    __syncthreads();
    for (int i = t; i < nE; i += 256) {
        int2 e = sm.b.st[i];
        int b2 = e.y >> SH;
        int slot = sm.b.gbase[b2] + (i - sm.b.lstart[b2]);
        slot = min(slot, (b2 + 1) * CAP_B - 1);   // overflow clamp
        coo[slot] = e;
    }
}

// ---------------- scanb: 391 bucket totals -> bbase; off[N]=ETOT ------------
__global__ __launch_bounds__(256) void k_scanb(const int* __restrict__ gcur,
                                               int* __restrict__ bbase,
                                               int* __restrict__ off) {
    __shared__ int tsum[256];
    int t = threadIdx.x;
    int i0 = 2 * t, i1 = 2 * t + 1;
    int a = 0, b = 0;
    if (i0 < NBUCK) a = min(gcur[i0], CAP_B) + min(256, N_NODES - (i0 << SH));
    if (i1 < NBUCK) b = min(gcur[i1], CAP_B) + min(256, N_NODES - (i1 << SH));
    int s = a + b;
    tsum[t] = s;
    __syncthreads();
    for (int ofs = 1; ofs < 256; ofs <<= 1) {
        int u = (t >= ofs) ? tsum[t - ofs] : 0;
        __syncthreads();
        tsum[t] += u;
        __syncthreads();
    }
    int pre = tsum[t] - s;
    if (i0 < NBUCK) bbase[i0] = pre;
    if (i1 < NBUCK) bbase[i1] = pre + a;
    if (t == 0) off[N_NODES] = ETOT;
}

// ---------------- kernel: fine (LDS reorder) || gemm1 part B ----------------
union SmemFine {
    struct {
        int ldeg[256];
        int lpre[256];
        int lsrc[CAP_B + 256];
    } f;
    unsigned short xb[64][136];
};

__global__ __launch_bounds__(256) void k_parFine(
    const int2* __restrict__ coo, const int* __restrict__ gcur,
    const int* __restrict__ bbase, int* __restrict__ off,
    int* __restrict__ csr,
    const float* __restrict__ x, const unsigned short* __restrict__ wtg,
    const float* __restrict__ asrc, const float* __restrict__ adst,
    __hip_bfloat16* __restrict__ h1b, float* __restrict__ s1,
    float* __restrict__ d1) {
    __shared__ SmemFine sm;
    int bid = blockIdx.x, t = threadIdx.x;
    bool isFine = (bid % 3 == 0) && (bid / 3 < NBUCK);
    if (!isFine) {                      // gemm role, gid 0..G_B-1
        int gid = bid - bid / 3 - 1;
        gemm1_role((G_A + gid) * 64, t, sm.xb, x, wtg, asrc, adst, h1b, s1, d1);
        return;
    }
    int b = bid / 3;
    int n0 = b << SH;
    int nn = min(256, N_NODES - n0);
    int ecnt = min(gcur[b], CAP_B);
    int base = bbase[b];
    const int2* seg = coo + (size_t)b * CAP_B;

    sm.f.ldeg[t] = 0;
    __syncthreads();
    for (int i = t; i < ecnt; i += 256)
        atomicAdd(&sm.f.ldeg[seg[i].y - n0], 1);
    __syncthreads();
    int d = (t < nn) ? sm.f.ldeg[t] + 1 : 0;   // +1 self-loop
    sm.f.lpre[t] = d;
    __syncthreads();
    for (int ofs = 1; ofs < 256; ofs <<= 1) {
        int u = (t >= ofs) ? sm.f.lpre[t - ofs] : 0;
        __syncthreads();
        sm.f.lpre[t] += u;
        __syncthreads();
    }
    int myoff = sm.f.lpre[t] - d;
    __syncthreads();
    if (t < nn) {
        off[n0 + t] = base + myoff;
        sm.f.lsrc[myoff] = n0 + t;
        sm.f.ldeg[t] = myoff + 1;
    }
    __syncthreads();
    for (int i = t; i < ecnt; i += 256) {
        int2 e = seg[i];
        int p = atomicAdd(&sm.f.ldeg[e.y - n0], 1);
        sm.f.lsrc[p] = e.x;
    }
    __syncthreads();
    int tot = ecnt + nn;
    for (int i = t; i < tot; i += 256)
        csr[base + i] = sm.f.lsrc[i];
}

// ---------------- layer 1 softmax-aggregate (dot2 pairs, 1-deep prefetch) ---
__global__ __launch_bounds__(256) void k_l1(
    const int* __restrict__ off, const int* __restrict__ csr,
    const float* __restrict__ s1, const float* __restrict__ d1,
    const uint4* __restrict__ h1q, const float* __restrict__ b1,
    float* __restrict__ emb) {
    int t = threadIdx.x;
    int node = blockIdx.x * 4 + (t >> 6);
    int l = t & 63;
    int g = l >> 4, q = l & 15;
    int hb = q >> 1;
    int lo = off[node], hi = off[node + 1];
    float dvh = d1[node * 8 + hb];

    float acc[8];
#pragma unroll
    for (int c = 0; c < 8; ++c) acc[c] = 0.f;
    float den = 0.f;

    int idx = lo + g;
    bool have = (idx + 4 < hi);
    int sa = 0, sb = 0;
    uint4 ba = make_uint4(0, 0, 0, 0), bb = make_uint4(0, 0, 0, 0);
    float sva = 0.f, svb = 0.f;
    if (have) {
        sa = csr[idx]; sb = csr[idx + 4];
        ba = h1q[(size_t)sa * 16 + q];
        bb = h1q[(size_t)sb * 16 + q];
        sva = s1[sa * 8 + hb];
        svb = s1[sb * 8 + hb];
    }
    while (have) {
        int nidx = idx + 8;
        bool nhave = (nidx + 4 < hi);
        int na = 0, nb = 0;
        uint4 nba = make_uint4(0, 0, 0, 0), nbb = make_uint4(0, 0, 0, 0);
        float nsa = 0.f, nsb = 0.f;
        if (nhave) {
            na = csr[nidx]; nb = csr[nidx + 4];
            nba = h1q[(size_t)na * 16 + q];
            nbb = h1q[(size_t)nb * 16 + q];
            nsa = s1[na * 8 + hb];
            nsb = s1[nb * 8 + hb];
        }
        float w0 = __expf(lrelu(sva + dvh));
        float w1 = __expf(lrelu(svb + dvh));
        den += w0 + w1;
        unsigned int wp;
        asm("v_cvt_pk_bf16_f32 %0, %1, %2" : "=v"(wp) : "v"(w0), "v"(w1));
        unsigned int p0, p1;
        p0 = __builtin_amdgcn_perm(bb.x, ba.x, 0x05040100u);
        p1 = __builtin_amdgcn_perm(bb.x, ba.x, 0x07060302u);
        acc[0] = dot2bf(wp, p0, acc[0]);
        acc[1] = dot2bf(wp, p1, acc[1]);
        p0 = __builtin_amdgcn_perm(bb.y, ba.y, 0x05040100u);
        p1 = __builtin_amdgcn_perm(bb.y, ba.y, 0x07060302u);
        acc[2] = dot2bf(wp, p0, acc[2]);
        acc[3] = dot2bf(wp, p1, acc[3]);
        p0 = __builtin_amdgcn_perm(bb.z, ba.z, 0x05040100u);
        p1 = __builtin_amdgcn_perm(bb.z, ba.z, 0x07060302u);
        acc[4] = dot2bf(wp, p0, acc[4]);
        acc[5] = dot2bf(wp, p1, acc[5]);
        p0 = __builtin_amdgcn_perm(bb.w, ba.w, 0x05040100u);
        p1 = __builtin_amdgcn_perm(bb.w, ba.w, 0x07060302u);
        acc[6] = dot2bf(wp, p0, acc[6]);
        acc[7] = dot2bf(wp, p1, acc[7]);
        sa = na; sb = nb; ba = nba; bb = nbb; sva = nsa; svb = nsb;
        idx = nidx; have = nhave;
    }
    if (idx < hi) {
        int sc = csr[idx];
        uint4 bv = h1q[(size_t)sc * 16 + q];
        float w = __expf(lrelu(s1[sc * 8 + hb] + dvh));
        den += w;
        acc[0] = fmaf(w, bflo(bv.x), acc[0]);
        acc[1] = fmaf(w, bfhi(bv.x), acc[1]);
        acc[2] = fmaf(w, bflo(bv.y), acc[2]);
        acc[3] = fmaf(w, bfhi(bv.y), acc[3]);
        acc[4] = fmaf(w, bflo(bv.z), acc[4]);
        acc[5] = fmaf(w, bfhi(bv.z), acc[5]);
        acc[6] = fmaf(w, bflo(bv.w), acc[6]);
        acc[7] = fmaf(w, bfhi(bv.w), acc[7]);
    }
#pragma unroll
    for (int c = 0; c < 8; ++c) {
        acc[c] += __shfl_xor(acc[c], 16, 64);
        acc[c] += __shfl_xor(acc[c], 32, 64);
    }
    den += __shfl_xor(den, 16, 64);
    den += __shfl_xor(den, 32, 64);

    if (l < 16) {
        float r = 1.f / den;
        float vv[8];
#pragma unroll
        for (int c = 0; c < 8; ++c) {
            float v = acc[c] * r + b1[8 * q + c];
            vv[c] = v > 0.f ? v : expm1f(v);
        }
        float4* ep = (float4*)(emb + (size_t)node * 128);
        ep[2 * q]     = make_float4(vv[0], vv[1], vv[2], vv[3]);
        ep[2 * q + 1] = make_float4(vv[4], vv[5], vv[6], vv[7]);
    }
}

// ---------------- layer 2 GEMM: h2(bf16) = emb @ W2 (128->16), s2/d2 --------
__global__ __launch_bounds__(256) void k_gemm2(
    const float* __restrict__ emb, const float* __restrict__ W,
    const float* __restrict__ asrc, const float* __restrict__ adst,
    __hip_bfloat16* __restrict__ h2b, float* __restrict__ s2,
    float* __restrict__ d2) {
    __shared__ float xs[16][129];
    int n0 = blockIdx.x * 16;
    int t = threadIdx.x;
#pragma unroll
    for (int i = 0; i < 8; ++i) {
        int idx = t + i * 256;
        xs[idx >> 7][idx & 127] = emb[(long)n0 * 128 + idx];
    }
    __syncthreads();
    int j = t & 15, sub = t >> 4;
    float acc = 0.f;
    for (int k = 0; k < 128; ++k) acc = fmaf(xs[sub][k], W[k * 16 + j], acc);
    int n = n0 + sub;
    h2b[(long)n * 16 + j] = __float2bfloat16(acc);
    float ps = acc * asrc[j], pd = acc * adst[j];
#pragma unroll
    for (int off = 8; off; off >>= 1) {
        ps += __shfl_down(ps, off, 16);
        pd += __shfl_down(pd, off, 16);
    }
    if (j == 0) { s2[n] = ps; d2[n] = pd; }
}

// ---------------- layer 2 single-pass aggregate + log_softmax ---------------
__global__ __launch_bounds__(256) void k_l2(
    const int* __restrict__ off, const int* __restrict__ csr,
    const float* __restrict__ s2, const float* __restrict__ d2,
    const unsigned int* __restrict__ h2w, const float* __restrict__ b2,
    float* __restrict__ logits) {
    int t = threadIdx.x;
    int node = blockIdx.x * 4 + (t >> 6);
    int l = t & 63;
    int g = l >> 3, p = l & 7;
    int lo = off[node], hi = off[node + 1];
    float dv = d2[node];

    float ax = 0.f, ay = 0.f, den = 0.f;
    for (int idx = lo + g; idx < hi; idx += 8) {
        int s = csr[idx];
        float w = __expf(lrelu(s2[s] + dv));
        den += w;
        unsigned int bv = h2w[(size_t)s * 8 + p];
        ax = fmaf(w, bflo(bv), ax);
        ay = fmaf(w, bfhi(bv), ay);
    }
#pragma unroll
    for (int ofs = 8; ofs < 64; ofs <<= 1) {
        ax += __shfl_xor(ax, ofs, 64);
        ay += __shfl_xor(ay, ofs, 64);
        den += __shfl_xor(den, ofs, 64);
    }
    float r = 1.f / den;
    float v0 = ax * r + b2[2 * p], v1 = ay * r + b2[2 * p + 1];
    float mm = fmaxf(v0, v1);
#pragma unroll
    for (int ofs = 1; ofs < 8; ofs <<= 1) mm = fmaxf(mm, __shfl_xor(mm, ofs, 8));
    float sm = __expf(v0 - mm) + __expf(v1 - mm);
#pragma unroll
    for (int ofs = 1; ofs < 8; ofs <<= 1) sm += __shfl_xor(sm, ofs, 8);
    if (g == 0) {
        float ls = logf(sm);
        logits[node * 16 + 2 * p]     = v0 - mm - ls;
        logits[node * 16 + 2 * p + 1] = v1 - mm - ls;
    }
}

extern "C" void kernel_launch(void* const* d_in, const int* in_sizes, int n_in,
                              void* d_out, int out_size, void* d_ws, size_t ws_size,
                              hipStream_t stream) {
    const float* x   = (const float*)d_in[0];
    const int*   ei  = (const int*)d_in[1];
    const float* W1  = (const float*)d_in[2];
    const float* as1 = (const float*)d_in[3];
    const float* ad1 = (const float*)d_in[4];
    const float* b1  = (const float*)d_in[5];
    const float* W2  = (const float*)d_in[6];
    const float* as2 = (const float*)d_in[7];
    const float* ad2 = (const float*)d_in[8];
    const float* b2  = (const float*)d_in[9];

    float* out    = (float*)d_out;
    float* logits = out;                          // [N,16]
    float* emb    = out + (size_t)N_NODES * 16;   // [N,128]

    float* ws    = (float*)d_ws;
    unsigned int* h1w = (unsigned int*)ws;                    // N*64 words (bf16 x2)
    int2*  coo   = (int2*)(h1w + (size_t)N_NODES * 64);      // NBUCK*CAP_B
    float* s1    = (float*)(coo + (size_t)NBUCK * CAP_B);     // N*8
    float* d1    = s1 + (size_t)N_NODES * 8;
    unsigned int* h2w = (unsigned int*)(d1 + (size_t)N_NODES * 8); // N*8 words
    float* s2    = (float*)(h2w + (size_t)N_NODES * 8);       // N
    float* d2v   = s2 + (size_t)N_NODES;
    int*   offs  = (int*)(d2v + (size_t)N_NODES);             // N+1
    int*   csr   = offs + N_NODES + 2;                        // ETOT
    int*   gcur  = csr + ETOT;                                // NBUCK
    int*   bbase = gcur + NBUCK;                              // NBUCK
    unsigned short* wtg = (unsigned short*)(bbase + NBUCK);   // 128*128 bf16

    const int* srcp = ei;
    const int* dstp = ei + E_EDGES;

    hipMemsetAsync(gcur, 0, (size_t)NBUCK * sizeof(int), stream);

    k_wt<<<64, 256, 0, stream>>>(W1, wtg);
    k_parBin<<<2 * NBIN, 256, 0, stream>>>(srcp, dstp, gcur, coo,
                                           x, wtg, as1, ad1,
                                           (__hip_bfloat16*)h1w, s1, d1);
    k_scanb<<<1, 256, 0, stream>>>(gcur, bbase, offs);
    k_parFine<<<NBUCK + G_B, 256, 0, stream>>>(coo, gcur, bbase, offs, csr,
                                               x, wtg, as1, ad1,
                                               (__hip_bfloat16*)h1w, s1, d1);

    k_l1<<<N_NODES / 4, 256, 0, stream>>>(offs, csr, s1, d1,
                                          (const uint4*)h1w, b1, emb);

    k_gemm2<<<N_NODES / 16, 256, 0, stream>>>(emb, W2, as2, ad2,
                                              (__hip_bfloat16*)h2w, s2, d2v);
    k_l2<<<N_NODES / 4, 256, 0, stream>>>(offs, csr, s2, d2v, h2w, b2, logits);
}